// Round 6
// baseline (815.134 us; speedup 1.0000x reference)
//
#include <hip/hip_runtime.h>
#include <math.h>

#define H 128
#define NEGS 0.01f

typedef __attribute__((ext_vector_type(8))) short short8;
typedef __attribute__((ext_vector_type(4))) float f32x4;

__device__ __forceinline__ float lrelu(float x){ return x >= 0.f ? x : NEGS*x; }
__device__ __forceinline__ float eluf(float x){ return x > 0.f ? x : expf(x)-1.f; }
__device__ __forceinline__ float sigm(float x){ return 1.f/(1.f+expf(-x)); }
__device__ __forceinline__ float wred(float v){
  #pragma unroll
  for (int off = 32; off > 0; off >>= 1) v += __shfl_xor(v, off, 64);
  return v;
}
__device__ __forceinline__ float wredmax(float v){
  #pragma unroll
  for (int off = 32; off > 0; off >>= 1) v = fmaxf(v, __shfl_xor(v, off, 64));
  return v;
}
__device__ __forceinline__ unsigned fenc(float f){
  unsigned u = __float_as_uint(f);
  return (u & 0x80000000u) ? ~u : (u | 0x80000000u);
}
__device__ __forceinline__ float fdec(unsigned v){
  return __uint_as_float((v & 0x80000000u) ? (v ^ 0x80000000u) : ~v);
}
__device__ __forceinline__ unsigned short f2bf(float f){
  unsigned u = __float_as_uint(f);
  u += 0x7fffu + ((u >> 16) & 1u);
  return (unsigned short)(u >> 16);
}
__device__ __forceinline__ float bf2f(unsigned short h){
  return __uint_as_float(((unsigned)h) << 16);
}
__device__ __forceinline__ float rdlane(float v, int l){
  return __int_as_float(__builtin_amdgcn_readlane(__float_as_int(v), l));
}
__device__ __forceinline__ int rdlanei(int v, int l){
  return __builtin_amdgcn_readlane(v, l);
}

// generic weight cast: dst[r*128+c] = bf16(src[r*ld+c])
__global__ void k_castw(const float* __restrict__ src, unsigned short* __restrict__ dst,
                        int rows, int ld){
  int idx = blockIdx.x*256 + threadIdx.x;
  if (idx >= rows*H) return;
  int r = idx >> 7, c = idx & 127;
  dst[idx] = f2bf(src[r*ld + c]);
}

// x[i,t] = lrelu(node_attr[i]*W_lin1[t] + b_lin1[t])  (bf16 out)
__global__ void k_node_init(const float* __restrict__ na, const float* __restrict__ wl,
                            const float* __restrict__ bl, unsigned short* __restrict__ x, int n){
  int idx = blockIdx.x*blockDim.x + threadIdx.x;
  if (idx >= n*H) return;
  int i = idx >> 7, t = idx & 127;
  x[idx] = f2bf(lrelu(na[i]*wl[t] + bl[t]));
}

// MFMA GEMM: Y[i*ldy + m] = sum_k X[i,k]*W[m,k]; bf16 in/out, f32 accum.
__global__ __launch_bounds__(256)
void k_gemm_mfma(const unsigned short* __restrict__ X, const unsigned short* __restrict__ Wbf,
                 unsigned short* __restrict__ Y, int n, int ldy){
  int w = threadIdx.x >> 6;
  int l = threadIdx.x & 63;
  int i0 = blockIdx.x*64 + w*16;
  int mbase = blockIdx.y*128;
  int row = l & 15;
  int kg  = l >> 4;
  f32x4 acc[8];
  #pragma unroll
  for (int c = 0; c < 8; ++c) acc[c] = (f32x4){0.f,0.f,0.f,0.f};
  int ai = i0 + row;
  bool av = (ai < n);
  #pragma unroll
  for (int ks = 0; ks < 4; ++ks){
    int koff = ks*32 + kg*8;
    short8 a = av ? *(const short8*)&X[(size_t)ai*H + koff]
                  : (short8){0,0,0,0,0,0,0,0};
    #pragma unroll
    for (int c = 0; c < 8; ++c){
      short8 b = *(const short8*)&Wbf[(size_t)(mbase + c*16 + row)*H + koff];
      acc[c] = __builtin_amdgcn_mfma_f32_16x16x32_bf16(a, b, acc[c], 0, 0, 0);
    }
  }
  #pragma unroll
  for (int c = 0; c < 8; ++c){
    #pragma unroll
    for (int r = 0; r < 4; ++r){
      int i = i0 + kg*4 + r;
      if (i < n) Y[(size_t)i*ldy + mbase + c*16 + row] = f2bf(acc[c][r]);
    }
  }
}

// Fused GRU: gi = hb@Wih.T (hb already elu'd), gh = x@Whh.T, then
// x = relu((1-z)*n + z*x) in place. 64 nodes/block, 48 MFMA accs per lane.
__global__ __launch_bounds__(256)
void k_gru_fused(const unsigned short* __restrict__ hb, unsigned short* __restrict__ x,
                 const unsigned short* __restrict__ Wih, const unsigned short* __restrict__ Whh,
                 const float* __restrict__ bih, const float* __restrict__ bhh, int n){
  int w = threadIdx.x >> 6;
  int l = threadIdx.x & 63;
  int i0 = blockIdx.x*64 + w*16;
  int row = l & 15;
  int kg  = l >> 4;
  f32x4 ai0[8], ai1[8], ai2[8], ah0[8], ah1[8], ah2[8];
  #pragma unroll
  for (int c = 0; c < 8; ++c){
    ai0[c]=(f32x4){0,0,0,0}; ai1[c]=(f32x4){0,0,0,0}; ai2[c]=(f32x4){0,0,0,0};
    ah0[c]=(f32x4){0,0,0,0}; ah1[c]=(f32x4){0,0,0,0}; ah2[c]=(f32x4){0,0,0,0};
  }
  int an = i0 + row;
  bool av = (an < n);
  #pragma unroll
  for (int ks = 0; ks < 4; ++ks){
    int koff = ks*32 + kg*8;
    short8 a1 = av ? *(const short8*)&hb[(size_t)an*H + koff] : (short8){0,0,0,0,0,0,0,0};
    short8 a2 = av ? *(const short8*)&x [(size_t)an*H + koff] : (short8){0,0,0,0,0,0,0,0};
    #pragma unroll
    for (int cc = 0; cc < 8; ++cc){
      int mrow = cc*16 + row;
      short8 b;
      b = *(const short8*)&Wih[(size_t)(mrow      )*H + koff];
      ai0[cc] = __builtin_amdgcn_mfma_f32_16x16x32_bf16(a1, b, ai0[cc], 0, 0, 0);
      b = *(const short8*)&Wih[(size_t)(mrow + 128)*H + koff];
      ai1[cc] = __builtin_amdgcn_mfma_f32_16x16x32_bf16(a1, b, ai1[cc], 0, 0, 0);
      b = *(const short8*)&Wih[(size_t)(mrow + 256)*H + koff];
      ai2[cc] = __builtin_amdgcn_mfma_f32_16x16x32_bf16(a1, b, ai2[cc], 0, 0, 0);
      b = *(const short8*)&Whh[(size_t)(mrow      )*H + koff];
      ah0[cc] = __builtin_amdgcn_mfma_f32_16x16x32_bf16(a2, b, ah0[cc], 0, 0, 0);
      b = *(const short8*)&Whh[(size_t)(mrow + 128)*H + koff];
      ah1[cc] = __builtin_amdgcn_mfma_f32_16x16x32_bf16(a2, b, ah1[cc], 0, 0, 0);
      b = *(const short8*)&Whh[(size_t)(mrow + 256)*H + koff];
      ah2[cc] = __builtin_amdgcn_mfma_f32_16x16x32_bf16(a2, b, ah2[cc], 0, 0, 0);
    }
  }
  #pragma unroll
  for (int cc = 0; cc < 8; ++cc){
    int t = cc*16 + row;
    float bir = bih[t], biz = bih[t+128], bin = bih[t+256];
    float bhr = bhh[t], bhz = bhh[t+128], bhn = bhh[t+256];
    #pragma unroll
    for (int r = 0; r < 4; ++r){
      int i = i0 + kg*4 + r;
      if (i < n){
        float ir = ai0[cc][r] + bir, iz = ai1[cc][r] + biz, inn = ai2[cc][r] + bin;
        float hr = ah0[cc][r] + bhr, hz = ah1[cc][r] + bhz, hn  = ah2[cc][r] + bhn;
        float rr = sigm(ir + hr), z = sigm(iz + hz);
        float nn = tanhf(inn + rr*hn);
        float xo = (1.f - z)*nn + z*bf2f(x[(size_t)i*H + t]);
        x[(size_t)i*H + t] = f2bf(fmaxf(xo, 0.f));
      }
    }
  }
}

// per-node dots with one or two 128-vectors (one wave per node), bf16 X
__global__ void k_rowdot2(const unsigned short* __restrict__ X, const float* __restrict__ v1,
                          const float* __restrict__ v2, float* __restrict__ o1,
                          float* __restrict__ o2, int n){
  int i = blockIdx.x*4 + (threadIdx.x >> 6);
  int lane = threadIdx.x & 63;
  if (i >= n) return;
  ushort2 u = *(const ushort2*)&X[(size_t)i*H + 2*lane];
  float x0 = bf2f(u.x), x1 = bf2f(u.y);
  float2 va = *(const float2*)&v1[2*lane];
  float a = x0*va.x + x1*va.y;
  float b = 0.f;
  if (v2){ float2 vb = *(const float2*)&v2[2*lane]; b = x0*vb.x + x1*vb.y; }
  a = wred(a);
  if (v2) b = wred(b);
  if (lane == 0){ o1[i] = a; if (v2) o2[i] = b; }
}

// ---------------- CSR build ----------------
__global__ void k_hist(const int* __restrict__ dst, int* __restrict__ deg, int ne){
  int e = blockIdx.x*blockDim.x + threadIdx.x;
  if (e < ne) atomicAdd(&deg[dst[e]], 1);
}
__global__ void k_scan1(const int* __restrict__ deg, int* __restrict__ bsum, int n){
  __shared__ int sd[256];
  int i = blockIdx.x*256 + threadIdx.x;
  sd[threadIdx.x] = (i < n) ? deg[i] : 0;
  __syncthreads();
  for (int s = 128; s > 0; s >>= 1){
    if (threadIdx.x < s) sd[threadIdx.x] += sd[threadIdx.x+s];
    __syncthreads();
  }
  if (threadIdx.x == 0) bsum[blockIdx.x] = sd[0];
}
__global__ void k_scan2(int* __restrict__ bsum, int nb){
  __shared__ int sd[256];
  int t = threadIdx.x;
  int v = (t < nb) ? bsum[t] : 0;
  sd[t] = v;
  __syncthreads();
  for (int off = 1; off < 256; off <<= 1){
    int u = (t >= off) ? sd[t-off] : 0;
    __syncthreads();
    sd[t] += u;
    __syncthreads();
  }
  if (t < nb) bsum[t] = sd[t] - v;
}
__global__ void k_scan3(const int* __restrict__ deg, const int* __restrict__ boff,
                        int* __restrict__ rowptr, int* __restrict__ cursor, int n){
  __shared__ int sd[256];
  int t = threadIdx.x;
  int i = blockIdx.x*256 + t;
  int v = (i < n) ? deg[i] : 0;
  sd[t] = v;
  __syncthreads();
  for (int off = 1; off < 256; off <<= 1){
    int u = (t >= off) ? sd[t-off] : 0;
    __syncthreads();
    sd[t] += u;
    __syncthreads();
  }
  int excl = sd[t] - v + boff[blockIdx.x];
  if (i < n){
    rowptr[i] = excl; cursor[i] = excl;
    if (i == n-1) rowptr[n] = excl + v;
  }
}
__global__ void k_fill(const int* __restrict__ dst, int* __restrict__ cursor,
                       int* __restrict__ eid, int ne){
  int e = blockIdx.x*blockDim.x + threadIdx.x;
  if (e >= ne) return;
  int pos = atomicAdd(&cursor[dst[e]], 1);
  eid[pos] = e;
}

// contiguous copy of gate_W1[:,128]
__global__ void k_pack_gate(const float* __restrict__ gateW1, float* __restrict__ w1col){
  int t = threadIdx.x;
  if (t < H) w1col[t] = gateW1[t*129 + 128];
}

// GATEConv edge logits, 16 lanes/edge, bf16 xW1
__global__ __launch_bounds__(256)
void k_edge_logit_gate(const unsigned short* __restrict__ xW1, const float* __restrict__ w1col,
                       const float* __restrict__ attl, const float* __restrict__ rdot,
                       const float* __restrict__ ea, const int* __restrict__ src,
                       const int* __restrict__ dst, float* __restrict__ logit, int ne){
  int tid = threadIdx.x;
  int e = blockIdx.x*16 + (tid >> 4);
  int g = tid & 15;
  if (e >= ne) return;
  int s = src[e];
  float eav = ea[e];
  short8 raw = *(const short8*)&xW1[(size_t)s*H + g*8];
  float4 w0 = *(const float4*)&w1col[g*8];
  float4 w1 = *(const float4*)&w1col[g*8 + 4];
  float4 a0 = *(const float4*)&attl[g*8];
  float4 a1 = *(const float4*)&attl[g*8 + 4];
  float acc = lrelu(bf2f((unsigned short)raw[0]) + eav*w0.x)*a0.x
            + lrelu(bf2f((unsigned short)raw[1]) + eav*w0.y)*a0.y
            + lrelu(bf2f((unsigned short)raw[2]) + eav*w0.z)*a0.z
            + lrelu(bf2f((unsigned short)raw[3]) + eav*w0.w)*a0.w
            + lrelu(bf2f((unsigned short)raw[4]) + eav*w1.x)*a1.x
            + lrelu(bf2f((unsigned short)raw[5]) + eav*w1.y)*a1.y
            + lrelu(bf2f((unsigned short)raw[6]) + eav*w1.z)*a1.z
            + lrelu(bf2f((unsigned short)raw[7]) + eav*w1.w)*a1.w;
  #pragma unroll
  for (int off = 1; off < 16; off <<= 1) acc += __shfl_xor(acc, off, 64);
  if (g == 0) logit[e] = lrelu(acc + rdot[dst[e]]);
}

// ---------------- per-node softmax + aggregation ----------------
// chunk-64 scheme: lane j computes w for edge c0+j (one expf/edge total),
// chunk sum via wred, serial gather loop broadcasts w/src via v_readlane.
__global__ void k_node_agg(const int* __restrict__ rowptr, const int* __restrict__ eid,
                           const int* __restrict__ src, const float* __restrict__ logit,
                           const unsigned short* __restrict__ val, const float* __restrict__ bias,
                           unsigned short* __restrict__ hbuf, int n){
  int i = blockIdx.x*4 + (threadIdx.x >> 6);
  int lane = threadIdx.x & 63;
  if (i >= n) return;
  int b = rowptr[i], e1 = rowptr[i+1];
  float m = -1e30f;
  for (int j = b+lane; j < e1; j += 64) m = fmaxf(m, logit[eid[j]]);
  m = wredmax(m);
  float s = 0.f, ax = 0.f, ay = 0.f;
  for (int c0 = b; c0 < e1; c0 += 64){
    int cnt = min(64, e1 - c0);
    float wv = 0.f; int snv = 0;
    if (lane < cnt){
      int e = eid[c0 + lane];
      snv = src[e];
      wv = expf(logit[e] - m);
    }
    s += wred(wv);
    int j = 0;
    for (; j+4 <= cnt; j += 4){
      float w0 = rdlane(wv,j), w1 = rdlane(wv,j+1), w2 = rdlane(wv,j+2), w3 = rdlane(wv,j+3);
      int s0 = rdlanei(snv,j), s1 = rdlanei(snv,j+1), s2 = rdlanei(snv,j+2), s3 = rdlanei(snv,j+3);
      ushort2 v0 = *(const ushort2*)&val[(size_t)s0*H + 2*lane];
      ushort2 v1 = *(const ushort2*)&val[(size_t)s1*H + 2*lane];
      ushort2 v2 = *(const ushort2*)&val[(size_t)s2*H + 2*lane];
      ushort2 v3 = *(const ushort2*)&val[(size_t)s3*H + 2*lane];
      ax += bf2f(v0.x)*w0 + bf2f(v1.x)*w1 + bf2f(v2.x)*w2 + bf2f(v3.x)*w3;
      ay += bf2f(v0.y)*w0 + bf2f(v1.y)*w1 + bf2f(v2.y)*w2 + bf2f(v3.y)*w3;
    }
    for (; j < cnt; ++j){
      float w0 = rdlane(wv,j);
      int s0 = rdlanei(snv,j);
      ushort2 v0 = *(const ushort2*)&val[(size_t)s0*H + 2*lane];
      ax += bf2f(v0.x)*w0; ay += bf2f(v0.y)*w0;
    }
  }
  float inv = (s > 0.f) ? 1.f/s : 0.f;
  ushort2 o;
  o.x = f2bf(eluf(bias[2*lane]   + ax*inv));
  o.y = f2bf(eluf(bias[2*lane+1] + ay*inv));
  *(ushort2*)&hbuf[(size_t)i*H + 2*lane] = o;
}

// GAT variant: logit = lrelu(ssrc[src]+sdst[i]) inline
__global__ void k_node_agg_gat(const int* __restrict__ rowptr, const int* __restrict__ eid,
                               const int* __restrict__ src, const float* __restrict__ ssrc,
                               const float* __restrict__ sdst, const unsigned short* __restrict__ val,
                               const float* __restrict__ bias, unsigned short* __restrict__ hbuf, int n){
  int i = blockIdx.x*4 + (threadIdx.x >> 6);
  int lane = threadIdx.x & 63;
  if (i >= n) return;
  int b = rowptr[i], e1 = rowptr[i+1];
  float sdi = sdst[i];
  float m = -1e30f;
  for (int j = b+lane; j < e1; j += 64) m = fmaxf(m, lrelu(ssrc[src[eid[j]]] + sdi));
  m = wredmax(m);
  float s = 0.f, ax = 0.f, ay = 0.f;
  for (int c0 = b; c0 < e1; c0 += 64){
    int cnt = min(64, e1 - c0);
    float wv = 0.f; int snv = 0;
    if (lane < cnt){
      snv = src[eid[c0 + lane]];
      wv = expf(lrelu(ssrc[snv] + sdi) - m);
    }
    s += wred(wv);
    int j = 0;
    for (; j+4 <= cnt; j += 4){
      float w0 = rdlane(wv,j), w1 = rdlane(wv,j+1), w2 = rdlane(wv,j+2), w3 = rdlane(wv,j+3);
      int s0 = rdlanei(snv,j), s1 = rdlanei(snv,j+1), s2 = rdlanei(snv,j+2), s3 = rdlanei(snv,j+3);
      ushort2 v0 = *(const ushort2*)&val[(size_t)s0*H + 2*lane];
      ushort2 v1 = *(const ushort2*)&val[(size_t)s1*H + 2*lane];
      ushort2 v2 = *(const ushort2*)&val[(size_t)s2*H + 2*lane];
      ushort2 v3 = *(const ushort2*)&val[(size_t)s3*H + 2*lane];
      ax += bf2f(v0.x)*w0 + bf2f(v1.x)*w1 + bf2f(v2.x)*w2 + bf2f(v3.x)*w3;
      ay += bf2f(v0.y)*w0 + bf2f(v1.y)*w1 + bf2f(v2.y)*w2 + bf2f(v3.y)*w3;
    }
    for (; j < cnt; ++j){
      float w0 = rdlane(wv,j);
      int s0 = rdlanei(snv,j);
      ushort2 v0 = *(const ushort2*)&val[(size_t)s0*H + 2*lane];
      ax += bf2f(v0.x)*w0; ay += bf2f(v0.y)*w0;
    }
  }
  float inv = (s > 0.f) ? 1.f/s : 0.f;
  ushort2 o;
  o.x = f2bf(eluf(bias[2*lane]   + ax*inv));
  o.y = f2bf(eluf(bias[2*lane+1] + ay*inv));
  *(ushort2*)&hbuf[(size_t)i*H + 2*lane] = o;
}

// ---------------- molecule readout ----------------
__global__ void k_colsum(const unsigned short* __restrict__ x, float* __restrict__ outraw,
                         int n, int chunk){
  int t = threadIdx.x; // 128
  int start = blockIdx.x*chunk;
  int end = min(start + chunk, n);
  float s = 0.f;
  for (int i = start; i < end; ++i) s += bf2f(x[(size_t)i*H + t]);
  if (start < end) atomicAdd(&outraw[t], s);
}
__global__ void k_mol_prep(const float* __restrict__ outraw, const float* __restrict__ molW,
                           const float* __restrict__ attdst, float* __restrict__ hidvec,
                           float* __restrict__ cdst){
  __shared__ float hs[128];
  __shared__ float red[128];
  int t = threadIdx.x;
  float hv = fmaxf(outraw[t], 0.f);
  hs[t] = hv; hidvec[t] = hv;
  __syncthreads();
  float o = 0.f;
  for (int k = 0; k < 128; ++k) o += hs[k]*molW[t*128+k];
  red[t] = o * attdst[t];
  __syncthreads();
  for (int s = 64; s > 0; s >>= 1){
    if (t < s) red[t] += red[t+s];
    __syncthreads();
  }
  if (t == 0) cdst[0] = red[0];
}
__global__ void k_mol_logit(float* __restrict__ a, const float* __restrict__ cdst,
                            unsigned* __restrict__ gmax, int n){
  int i = blockIdx.x*blockDim.x + threadIdx.x;
  if (i >= n) return;
  float l = lrelu(a[i] + cdst[0]);
  a[i] = l;
  atomicMax(gmax, fenc(l));
}
__global__ void k_mol_exp(float* __restrict__ a, const unsigned* __restrict__ gmax,
                          float* __restrict__ gsum, int n){
  int i = blockIdx.x*blockDim.x + threadIdx.x;
  int lane = threadIdx.x & 63;
  float gm = fdec(gmax[0]);
  float ex = 0.f;
  if (i < n){ ex = expf(a[i] - gm); a[i] = ex; }
  float s = wred(ex);
  if (lane == 0) atomicAdd(gsum, s);
}
__global__ void k_mol_acc(const unsigned short* __restrict__ xs, const float* __restrict__ a,
                          float* __restrict__ num, int n, int chunk){
  int t = threadIdx.x; // 128
  int start = blockIdx.x*chunk;
  int end = min(start + chunk, n);
  float s = 0.f;
  for (int i = start; i < end; ++i) s += bf2f(xs[(size_t)i*H + t])*a[i];
  if (start < end) atomicAdd(&num[t], s);
}
__global__ void k_mol_final(const float* __restrict__ num, const float* __restrict__ gsum,
                            const float* __restrict__ molb, const float* __restrict__ hidvec,
                            const float* __restrict__ Wih, const float* __restrict__ Whh,
                            const float* __restrict__ bih, const float* __restrict__ bhh,
                            float* __restrict__ out){
  __shared__ float hv[128], hd[128];
  int t = threadIdx.x;
  hv[t] = eluf(num[t]/gsum[0] + molb[t]);
  hd[t] = hidvec[t];
  __syncthreads();
  float gr = bih[t], gz = bih[t+128], gn = bih[t+256];
  float hr = bhh[t], hz = bhh[t+128], hn = bhh[t+256];
  for (int k = 0; k < 128; ++k){
    float h = hv[k], d = hd[k];
    gr += h*Wih[t*128+k];       gz += h*Wih[(t+128)*128+k]; gn += h*Wih[(t+256)*128+k];
    hr += d*Whh[t*128+k];       hz += d*Whh[(t+128)*128+k]; hn += d*Whh[(t+256)*128+k];
  }
  float r = sigm(gr+hr), z = sigm(gz+hz);
  float nn = tanhf(gn + r*hn);
  float o = (1.f-z)*nn + z*hd[t];
  out[t] = fmaxf(o, 0.f);
}

extern "C" void kernel_launch(void* const* d_in, const int* in_sizes, int n_in,
                              void* d_out, int out_size, void* d_ws, size_t ws_size,
                              hipStream_t stream){
  const float* node_attr = (const float*)d_in[0];
  const int*   eidx      = (const int*)d_in[1];
  const float* eattr     = (const float*)d_in[2];
  const float* W_lin1    = (const float*)d_in[3];
  const float* b_lin1    = (const float*)d_in[4];
  const float* gate_W1   = (const float*)d_in[5];
  const float* gate_W2   = (const float*)d_in[6];
  const float* gate_att_l= (const float*)d_in[7];
  const float* gate_att_r= (const float*)d_in[8];
  const float* gate_b    = (const float*)d_in[9];
  const float* g1_Wih    = (const float*)d_in[10];
  const float* g1_Whh    = (const float*)d_in[11];
  const float* g1_bih    = (const float*)d_in[12];
  const float* g1_bhh    = (const float*)d_in[13];
  const float* atom_W    = (const float*)d_in[14];
  const float* atom_as   = (const float*)d_in[15];
  const float* atom_ad   = (const float*)d_in[16];
  const float* atom_b    = (const float*)d_in[17];
  const float* g2_Wih    = (const float*)d_in[18];
  const float* g2_Whh    = (const float*)d_in[19];
  const float* g2_bih    = (const float*)d_in[20];
  const float* g2_bhh    = (const float*)d_in[21];
  const float* mol_W     = (const float*)d_in[22];
  const float* mol_as    = (const float*)d_in[23];
  const float* mol_ad    = (const float*)d_in[24];
  const float* mol_b     = (const float*)d_in[25];
  const float* gm_Wih    = (const float*)d_in[26];
  const float* gm_Whh    = (const float*)d_in[27];
  const float* gm_bih    = (const float*)d_in[28];
  const float* gm_bhh    = (const float*)d_in[29];

  const int n  = in_sizes[0];
  const int ne = in_sizes[1] / 2;
  const int* src = eidx;
  const int* dst = eidx + ne;

  // ---- workspace layout ----
  const size_t NH = (size_t)n * H;
  unsigned short* us = (unsigned short*)d_ws;
  unsigned short* x_bf = us;            // [N,H]
  unsigned short* t0   = us + NH;       // [N,H]
  unsigned short* t1   = us + 2*NH;     // [N,H]
  unsigned short* hb   = us + 3*NH;     // [N,H]
  float* fb = (float*)(us + 4*NH);
  float* rdot = fb;                     // [N]
  float* ssrc = rdot + n;               // [N]
  float* sdst = ssrc + n;               // [N]
  float* ealpha = sdst + n;             // [E]
  int* deg    = (int*)(ealpha + ne);    // [N]
  int* cursor = deg + n;                // [N]
  int* rowptr = cursor + n;             // [N+1]
  int* bsum   = rowptr + n + 1;         // [256]
  int* eid    = bsum + 256;             // [E]
  float* outraw = (float*)(eid + ne);   // [128]
  float* hidvec = outraw + 128;         // [128]
  float* cdstp  = hidvec + 128;         // [1]
  unsigned* gmax = (unsigned*)(cdstp + 1);
  float* gsum   = (float*)gmax + 1;
  float* numv   = gsum + 1;             // [128]
  float* w1col  = numv + 128;           // [128]
  unsigned short* wp = (unsigned short*)(w1col + 128);
  unsigned short* gW1bf  = wp;                 // 128*128
  unsigned short* gW2bf  = gW1bf  + 128*H;
  unsigned short* atomWbf= gW2bf  + 128*H;
  unsigned short* molWbf = atomWbf+ 128*H;
  unsigned short* g1ihbf = molWbf + 128*H;     // 384*128
  unsigned short* g1hhbf = g1ihbf + 384*H;
  unsigned short* g2ihbf = g1hhbf + 384*H;
  unsigned short* g2hhbf = g2ihbf + 384*H;

  const int nh_blocks  = (n*H + 255)/256;
  const int nb64       = (n + 63)/64;
  const int nwave4     = (n + 3)/4;
  const int e16_blocks = (ne + 15)/16;
  const int ethr       = (ne + 255)/256;
  const int nthr       = (n + 255)/256;
  const int nb         = (n + 255)/256;
  const int chunk      = (n + 255)/256;
  const int wcast128   = (128*H + 255)/256;
  const int wcast384   = (384*H + 255)/256;

  // ---- weight casts + CSR build + node init ----
  k_castw<<<wcast128,256,0,stream>>>(gate_W1, gW1bf, 128, 129);
  k_castw<<<wcast128,256,0,stream>>>(gate_W2, gW2bf, 128, 128);
  k_castw<<<wcast128,256,0,stream>>>(atom_W, atomWbf, 128, 128);
  k_castw<<<wcast128,256,0,stream>>>(mol_W, molWbf, 128, 128);
  k_castw<<<wcast384,256,0,stream>>>(g1_Wih, g1ihbf, 384, 128);
  k_castw<<<wcast384,256,0,stream>>>(g1_Whh, g1hhbf, 384, 128);
  k_castw<<<wcast384,256,0,stream>>>(g2_Wih, g2ihbf, 384, 128);
  k_castw<<<wcast384,256,0,stream>>>(g2_Whh, g2hhbf, 384, 128);
  k_pack_gate<<<1,128,0,stream>>>(gate_W1, w1col);
  k_node_init<<<nh_blocks,256,0,stream>>>(node_attr, W_lin1, b_lin1, x_bf, n);
  hipMemsetAsync(deg, 0, (size_t)n*4, stream);
  k_hist<<<ethr,256,0,stream>>>(dst, deg, ne);
  k_scan1<<<nb,256,0,stream>>>(deg, bsum, n);
  k_scan2<<<1,256,0,stream>>>(bsum, nb);
  k_scan3<<<nb,256,0,stream>>>(deg, bsum, rowptr, cursor, n);
  k_fill<<<ethr,256,0,stream>>>(dst, cursor, eid, ne);

  // ---- GATEConv ----
  k_gemm_mfma<<<dim3(nb64,1),256,0,stream>>>(x_bf, gW1bf, t0, n, H);   // xW1
  k_gemm_mfma<<<dim3(nb64,1),256,0,stream>>>(x_bf, gW2bf, t1, n, H);   // xW2
  k_rowdot2<<<nwave4,256,0,stream>>>(x_bf, gate_att_r, nullptr, rdot, nullptr, n);
  k_edge_logit_gate<<<e16_blocks,256,0,stream>>>(t0, w1col, gate_att_l, rdot, eattr,
                                                 src, dst, ealpha, ne);
  k_node_agg<<<nwave4,256,0,stream>>>(rowptr, eid, src, ealpha, t1, gate_b, hb, n);
  k_gru_fused<<<nb64,256,0,stream>>>(hb, x_bf, g1ihbf, g1hhbf, g1_bih, g1_bhh, n);

  // ---- GATConv ----
  k_gemm_mfma<<<dim3(nb64,1),256,0,stream>>>(x_bf, atomWbf, t0, n, H); // xt
  k_rowdot2<<<nwave4,256,0,stream>>>(t0, atom_as, atom_ad, ssrc, sdst, n);
  k_node_agg_gat<<<nwave4,256,0,stream>>>(rowptr, eid, src, ssrc, sdst, t0, atom_b, hb, n);
  k_gru_fused<<<nb64,256,0,stream>>>(hb, x_bf, g2ihbf, g2hhbf, g2_bih, g2_bhh, n);

  // ---- molecule readout ----
  hipMemsetAsync(outraw, 0, 128*4, stream);
  hipMemsetAsync(gmax, 0, 4, stream);
  hipMemsetAsync(gsum, 0, 4, stream);
  hipMemsetAsync(numv, 0, 128*4, stream);
  k_colsum<<<256,128,0,stream>>>(x_bf, outraw, n, chunk);
  k_mol_prep<<<1,128,0,stream>>>(outraw, mol_W, mol_ad, hidvec, cdstp);
  k_gemm_mfma<<<dim3(nb64,1),256,0,stream>>>(x_bf, molWbf, t1, n, H);  // xs
  k_rowdot2<<<nwave4,256,0,stream>>>(t1, mol_as, nullptr, rdot, nullptr, n);
  k_mol_logit<<<nthr,256,0,stream>>>(rdot, cdstp, gmax, n);
  k_mol_exp<<<nthr,256,0,stream>>>(rdot, gmax, gsum, n);
  k_mol_acc<<<256,128,0,stream>>>(t1, rdot, numv, n, chunk);
  k_mol_final<<<1,128,0,stream>>>(numv, gsum, mol_b, hidvec,
                                  gm_Wih, gm_Whh, gm_bih, gm_bhh, (float*)d_out);
}

// Round 7
// 764.861 us; speedup vs baseline: 1.0657x; 1.0657x over previous
//
#include <hip/hip_runtime.h>
#include <math.h>

#define H 128
#define NEGS 0.01f

typedef __attribute__((ext_vector_type(8))) short short8;
typedef __attribute__((ext_vector_type(4))) float f32x4;

__device__ __forceinline__ float lrelu(float x){ return x >= 0.f ? x : NEGS*x; }
__device__ __forceinline__ float eluf(float x){ return x > 0.f ? x : expf(x)-1.f; }
__device__ __forceinline__ float sigm(float x){ return 1.f/(1.f+expf(-x)); }
__device__ __forceinline__ float wred(float v){
  #pragma unroll
  for (int off = 32; off > 0; off >>= 1) v += __shfl_xor(v, off, 64);
  return v;
}
__device__ __forceinline__ float wredmax(float v){
  #pragma unroll
  for (int off = 32; off > 0; off >>= 1) v = fmaxf(v, __shfl_xor(v, off, 64));
  return v;
}
__device__ __forceinline__ unsigned fenc(float f){
  unsigned u = __float_as_uint(f);
  return (u & 0x80000000u) ? ~u : (u | 0x80000000u);
}
__device__ __forceinline__ float fdec(unsigned v){
  return __uint_as_float((v & 0x80000000u) ? (v ^ 0x80000000u) : ~v);
}
__device__ __forceinline__ unsigned short f2bf(float f){
  unsigned u = __float_as_uint(f);
  u += 0x7fffu + ((u >> 16) & 1u);
  return (unsigned short)(u >> 16);
}
__device__ __forceinline__ float bf2f(unsigned short h){
  return __uint_as_float(((unsigned)h) << 16);
}
__device__ __forceinline__ float rdlane(float v, int l){
  return __int_as_float(__builtin_amdgcn_readlane(__float_as_int(v), l));
}
__device__ __forceinline__ int rdlanei(int v, int l){
  return __builtin_amdgcn_readlane(v, l);
}

// generic weight cast: dst[r*128+c] = bf16(src[r*ld+c])
__global__ void k_castw(const float* __restrict__ src, unsigned short* __restrict__ dst,
                        int rows, int ld){
  int idx = blockIdx.x*256 + threadIdx.x;
  if (idx >= rows*H) return;
  int r = idx >> 7, c = idx & 127;
  dst[idx] = f2bf(src[r*ld + c]);
}

// x[i,t] = lrelu(node_attr[i]*W_lin1[t] + b_lin1[t])  (bf16 out)
__global__ void k_node_init(const float* __restrict__ na, const float* __restrict__ wl,
                            const float* __restrict__ bl, unsigned short* __restrict__ x, int n){
  int idx = blockIdx.x*blockDim.x + threadIdx.x;
  if (idx >= n*H) return;
  int i = idx >> 7, t = idx & 127;
  x[idx] = f2bf(lrelu(na[i]*wl[t] + bl[t]));
}

// MFMA GEMM: Y[i*ldy + mbase + m] = sum_k X[i,k]*W[mbase+m,k]; bf16 in/out, f32 accum.
// grid.x = ceil(n/64), grid.y = M/128. block 256 = 4 waves, 16 nodes/wave.
__global__ __launch_bounds__(256)
void k_gemm_mfma(const unsigned short* __restrict__ X, const unsigned short* __restrict__ Wbf,
                 unsigned short* __restrict__ Y, int n, int ldy){
  int w = threadIdx.x >> 6;
  int l = threadIdx.x & 63;
  int i0 = blockIdx.x*64 + w*16;
  int mbase = blockIdx.y*128;
  int row = l & 15;
  int kg  = l >> 4;
  f32x4 acc[8];
  #pragma unroll
  for (int c = 0; c < 8; ++c) acc[c] = (f32x4){0.f,0.f,0.f,0.f};
  int ai = i0 + row;
  bool av = (ai < n);
  #pragma unroll
  for (int ks = 0; ks < 4; ++ks){
    int koff = ks*32 + kg*8;
    short8 a = av ? *(const short8*)&X[(size_t)ai*H + koff]
                  : (short8){0,0,0,0,0,0,0,0};
    #pragma unroll
    for (int c = 0; c < 8; ++c){
      short8 b = *(const short8*)&Wbf[(size_t)(mbase + c*16 + row)*H + koff];
      acc[c] = __builtin_amdgcn_mfma_f32_16x16x32_bf16(a, b, acc[c], 0, 0, 0);
    }
  }
  #pragma unroll
  for (int c = 0; c < 8; ++c){
    #pragma unroll
    for (int r = 0; r < 4; ++r){
      int i = i0 + kg*4 + r;
      if (i < n) Y[(size_t)i*ldy + mbase + c*16 + row] = f2bf(acc[c][r]);
    }
  }
}

// GRUCell combine (bf16 gi/gh/x): x = relu((1-z)*n + z*x)
__global__ void k_gru_combine(const unsigned short* __restrict__ gi, const unsigned short* __restrict__ gh,
                              const float* __restrict__ bih, const float* __restrict__ bhh,
                              unsigned short* __restrict__ x, int n){
  int idx = blockIdx.x*blockDim.x + threadIdx.x;
  if (idx >= n*H) return;
  int i = idx >> 7, t = idx & 127;
  const unsigned short* gir = gi + (size_t)i*384;
  const unsigned short* ghr = gh + (size_t)i*384;
  float ir = bf2f(gir[t]) + bih[t], iz = bf2f(gir[t+128]) + bih[t+128], in = bf2f(gir[t+256]) + bih[t+256];
  float hr = bf2f(ghr[t]) + bhh[t], hz = bf2f(ghr[t+128]) + bhh[t+128], hn = bf2f(ghr[t+256]) + bhh[t+256];
  float r = sigm(ir + hr), z = sigm(iz + hz);
  float nn = tanhf(in + r*hn);
  float xo = (1.f - z)*nn + z*bf2f(x[idx]);
  x[idx] = f2bf(fmaxf(xo, 0.f));
}

// per-node dots with one or two 128-vectors (one wave per node), bf16 X
__global__ void k_rowdot2(const unsigned short* __restrict__ X, const float* __restrict__ v1,
                          const float* __restrict__ v2, float* __restrict__ o1,
                          float* __restrict__ o2, int n){
  int i = blockIdx.x*4 + (threadIdx.x >> 6);
  int lane = threadIdx.x & 63;
  if (i >= n) return;
  ushort2 u = *(const ushort2*)&X[(size_t)i*H + 2*lane];
  float x0 = bf2f(u.x), x1 = bf2f(u.y);
  float2 va = *(const float2*)&v1[2*lane];
  float a = x0*va.x + x1*va.y;
  float b = 0.f;
  if (v2){ float2 vb = *(const float2*)&v2[2*lane]; b = x0*vb.x + x1*vb.y; }
  a = wred(a);
  if (v2) b = wred(b);
  if (lane == 0){ o1[i] = a; if (v2) o2[i] = b; }
}

// ---------------- CSR build ----------------
__global__ void k_hist(const int* __restrict__ dst, int* __restrict__ deg, int ne){
  int e = blockIdx.x*blockDim.x + threadIdx.x;
  if (e < ne) atomicAdd(&deg[dst[e]], 1);
}
__global__ void k_scan1(const int* __restrict__ deg, int* __restrict__ bsum, int n){
  __shared__ int sd[256];
  int i = blockIdx.x*256 + threadIdx.x;
  sd[threadIdx.x] = (i < n) ? deg[i] : 0;
  __syncthreads();
  for (int s = 128; s > 0; s >>= 1){
    if (threadIdx.x < s) sd[threadIdx.x] += sd[threadIdx.x+s];
    __syncthreads();
  }
  if (threadIdx.x == 0) bsum[blockIdx.x] = sd[0];
}
__global__ void k_scan2(int* __restrict__ bsum, int nb){
  __shared__ int sd[256];
  int t = threadIdx.x;
  int v = (t < nb) ? bsum[t] : 0;
  sd[t] = v;
  __syncthreads();
  for (int off = 1; off < 256; off <<= 1){
    int u = (t >= off) ? sd[t-off] : 0;
    __syncthreads();
    sd[t] += u;
    __syncthreads();
  }
  if (t < nb) bsum[t] = sd[t] - v;
}
__global__ void k_scan3(const int* __restrict__ deg, const int* __restrict__ boff,
                        int* __restrict__ rowptr, int* __restrict__ cursor, int n){
  __shared__ int sd[256];
  int t = threadIdx.x;
  int i = blockIdx.x*256 + t;
  int v = (i < n) ? deg[i] : 0;
  sd[t] = v;
  __syncthreads();
  for (int off = 1; off < 256; off <<= 1){
    int u = (t >= off) ? sd[t-off] : 0;
    __syncthreads();
    sd[t] += u;
    __syncthreads();
  }
  int excl = sd[t] - v + boff[blockIdx.x];
  if (i < n){
    rowptr[i] = excl; cursor[i] = excl;
    if (i == n-1) rowptr[n] = excl + v;
  }
}
__global__ void k_fill(const int* __restrict__ dst, int* __restrict__ cursor,
                       int* __restrict__ eid, int ne){
  int e = blockIdx.x*blockDim.x + threadIdx.x;
  if (e >= ne) return;
  int pos = atomicAdd(&cursor[dst[e]], 1);
  eid[pos] = e;
}

// contiguous copy of gate_W1[:,128]
__global__ void k_pack_gate(const float* __restrict__ gateW1, float* __restrict__ w1col){
  int t = threadIdx.x;
  if (t < H) w1col[t] = gateW1[t*129 + 128];
}

// GATEConv edge logits, 16 lanes/edge, bf16 xW1
__global__ __launch_bounds__(256)
void k_edge_logit_gate(const unsigned short* __restrict__ xW1, const float* __restrict__ w1col,
                       const float* __restrict__ attl, const float* __restrict__ rdot,
                       const float* __restrict__ ea, const int* __restrict__ src,
                       const int* __restrict__ dst, float* __restrict__ logit, int ne){
  int tid = threadIdx.x;
  int e = blockIdx.x*16 + (tid >> 4);
  int g = tid & 15;
  if (e >= ne) return;
  int s = src[e];
  float eav = ea[e];
  short8 raw = *(const short8*)&xW1[(size_t)s*H + g*8];
  float4 w0 = *(const float4*)&w1col[g*8];
  float4 w1 = *(const float4*)&w1col[g*8 + 4];
  float4 a0 = *(const float4*)&attl[g*8];
  float4 a1 = *(const float4*)&attl[g*8 + 4];
  float acc = lrelu(bf2f((unsigned short)raw[0]) + eav*w0.x)*a0.x
            + lrelu(bf2f((unsigned short)raw[1]) + eav*w0.y)*a0.y
            + lrelu(bf2f((unsigned short)raw[2]) + eav*w0.z)*a0.z
            + lrelu(bf2f((unsigned short)raw[3]) + eav*w0.w)*a0.w
            + lrelu(bf2f((unsigned short)raw[4]) + eav*w1.x)*a1.x
            + lrelu(bf2f((unsigned short)raw[5]) + eav*w1.y)*a1.y
            + lrelu(bf2f((unsigned short)raw[6]) + eav*w1.z)*a1.z
            + lrelu(bf2f((unsigned short)raw[7]) + eav*w1.w)*a1.w;
  #pragma unroll
  for (int off = 1; off < 16; off <<= 1) acc += __shfl_xor(acc, off, 64);
  if (g == 0) logit[e] = lrelu(acc + rdot[dst[e]]);
}

// ---------------- per-node softmax + aggregation ----------------
// chunk-64 scheme: lane j computes w for edge c0+j (one expf/edge total),
// chunk sum via wred, serial gather loop broadcasts w/src via v_readlane.
__global__ void k_node_agg(const int* __restrict__ rowptr, const int* __restrict__ eid,
                           const int* __restrict__ src, const float* __restrict__ logit,
                           const unsigned short* __restrict__ val, const float* __restrict__ bias,
                           unsigned short* __restrict__ hbuf, int n){
  int i = blockIdx.x*4 + (threadIdx.x >> 6);
  int lane = threadIdx.x & 63;
  if (i >= n) return;
  int b = rowptr[i], e1 = rowptr[i+1];
  float m = -1e30f;
  for (int j = b+lane; j < e1; j += 64) m = fmaxf(m, logit[eid[j]]);
  m = wredmax(m);
  float s = 0.f, ax = 0.f, ay = 0.f;
  for (int c0 = b; c0 < e1; c0 += 64){
    int cnt = min(64, e1 - c0);
    float wv = 0.f; int snv = 0;
    if (lane < cnt){
      int e = eid[c0 + lane];
      snv = src[e];
      wv = expf(logit[e] - m);
    }
    s += wred(wv);
    int j = 0;
    for (; j+4 <= cnt; j += 4){
      float w0 = rdlane(wv,j), w1 = rdlane(wv,j+1), w2 = rdlane(wv,j+2), w3 = rdlane(wv,j+3);
      int s0 = rdlanei(snv,j), s1 = rdlanei(snv,j+1), s2 = rdlanei(snv,j+2), s3 = rdlanei(snv,j+3);
      ushort2 v0 = *(const ushort2*)&val[(size_t)s0*H + 2*lane];
      ushort2 v1 = *(const ushort2*)&val[(size_t)s1*H + 2*lane];
      ushort2 v2 = *(const ushort2*)&val[(size_t)s2*H + 2*lane];
      ushort2 v3 = *(const ushort2*)&val[(size_t)s3*H + 2*lane];
      ax += bf2f(v0.x)*w0 + bf2f(v1.x)*w1 + bf2f(v2.x)*w2 + bf2f(v3.x)*w3;
      ay += bf2f(v0.y)*w0 + bf2f(v1.y)*w1 + bf2f(v2.y)*w2 + bf2f(v3.y)*w3;
    }
    for (; j < cnt; ++j){
      float w0 = rdlane(wv,j);
      int s0 = rdlanei(snv,j);
      ushort2 v0 = *(const ushort2*)&val[(size_t)s0*H + 2*lane];
      ax += bf2f(v0.x)*w0; ay += bf2f(v0.y)*w0;
    }
  }
  float inv = (s > 0.f) ? 1.f/s : 0.f;
  ushort2 o;
  o.x = f2bf(eluf(bias[2*lane]   + ax*inv));
  o.y = f2bf(eluf(bias[2*lane+1] + ay*inv));
  *(ushort2*)&hbuf[(size_t)i*H + 2*lane] = o;
}

// GAT variant: logit = lrelu(ssrc[src]+sdst[i]) inline
__global__ void k_node_agg_gat(const int* __restrict__ rowptr, const int* __restrict__ eid,
                               const int* __restrict__ src, const float* __restrict__ ssrc,
                               const float* __restrict__ sdst, const unsigned short* __restrict__ val,
                               const float* __restrict__ bias, unsigned short* __restrict__ hbuf, int n){
  int i = blockIdx.x*4 + (threadIdx.x >> 6);
  int lane = threadIdx.x & 63;
  if (i >= n) return;
  int b = rowptr[i], e1 = rowptr[i+1];
  float sdi = sdst[i];
  float m = -1e30f;
  for (int j = b+lane; j < e1; j += 64) m = fmaxf(m, lrelu(ssrc[src[eid[j]]] + sdi));
  m = wredmax(m);
  float s = 0.f, ax = 0.f, ay = 0.f;
  for (int c0 = b; c0 < e1; c0 += 64){
    int cnt = min(64, e1 - c0);
    float wv = 0.f; int snv = 0;
    if (lane < cnt){
      snv = src[eid[c0 + lane]];
      wv = expf(lrelu(ssrc[snv] + sdi) - m);
    }
    s += wred(wv);
    int j = 0;
    for (; j+4 <= cnt; j += 4){
      float w0 = rdlane(wv,j), w1 = rdlane(wv,j+1), w2 = rdlane(wv,j+2), w3 = rdlane(wv,j+3);
      int s0 = rdlanei(snv,j), s1 = rdlanei(snv,j+1), s2 = rdlanei(snv,j+2), s3 = rdlanei(snv,j+3);
      ushort2 v0 = *(const ushort2*)&val[(size_t)s0*H + 2*lane];
      ushort2 v1 = *(const ushort2*)&val[(size_t)s1*H + 2*lane];
      ushort2 v2 = *(const ushort2*)&val[(size_t)s2*H + 2*lane];
      ushort2 v3 = *(const ushort2*)&val[(size_t)s3*H + 2*lane];
      ax += bf2f(v0.x)*w0 + bf2f(v1.x)*w1 + bf2f(v2.x)*w2 + bf2f(v3.x)*w3;
      ay += bf2f(v0.y)*w0 + bf2f(v1.y)*w1 + bf2f(v2.y)*w2 + bf2f(v3.y)*w3;
    }
    for (; j < cnt; ++j){
      float w0 = rdlane(wv,j);
      int s0 = rdlanei(snv,j);
      ushort2 v0 = *(const ushort2*)&val[(size_t)s0*H + 2*lane];
      ax += bf2f(v0.x)*w0; ay += bf2f(v0.y)*w0;
    }
  }
  float inv = (s > 0.f) ? 1.f/s : 0.f;
  ushort2 o;
  o.x = f2bf(eluf(bias[2*lane]   + ax*inv));
  o.y = f2bf(eluf(bias[2*lane+1] + ay*inv));
  *(ushort2*)&hbuf[(size_t)i*H + 2*lane] = o;
}

// ---------------- molecule readout ----------------
__global__ void k_colsum(const unsigned short* __restrict__ x, float* __restrict__ outraw,
                         int n, int chunk){
  int t = threadIdx.x; // 128
  int start = blockIdx.x*chunk;
  int end = min(start + chunk, n);
  float s = 0.f;
  for (int i = start; i < end; ++i) s += bf2f(x[(size_t)i*H + t]);
  if (start < end) atomicAdd(&outraw[t], s);
}
__global__ void k_mol_prep(const float* __restrict__ outraw, const float* __restrict__ molW,
                           const float* __restrict__ attdst, float* __restrict__ hidvec,
                           float* __restrict__ cdst){
  __shared__ float hs[128];
  __shared__ float red[128];
  int t = threadIdx.x;
  float hv = fmaxf(outraw[t], 0.f);
  hs[t] = hv; hidvec[t] = hv;
  __syncthreads();
  float o = 0.f;
  for (int k = 0; k < 128; ++k) o += hs[k]*molW[t*128+k];
  red[t] = o * attdst[t];
  __syncthreads();
  for (int s = 64; s > 0; s >>= 1){
    if (t < s) red[t] += red[t+s];
    __syncthreads();
  }
  if (t == 0) cdst[0] = red[0];
}
__global__ void k_mol_logit(float* __restrict__ a, const float* __restrict__ cdst,
                            unsigned* __restrict__ gmax, int n){
  int i = blockIdx.x*blockDim.x + threadIdx.x;
  if (i >= n) return;
  float l = lrelu(a[i] + cdst[0]);
  a[i] = l;
  atomicMax(gmax, fenc(l));
}
__global__ void k_mol_exp(float* __restrict__ a, const unsigned* __restrict__ gmax,
                          float* __restrict__ gsum, int n){
  int i = blockIdx.x*blockDim.x + threadIdx.x;
  int lane = threadIdx.x & 63;
  float gm = fdec(gmax[0]);
  float ex = 0.f;
  if (i < n){ ex = expf(a[i] - gm); a[i] = ex; }
  float s = wred(ex);
  if (lane == 0) atomicAdd(gsum, s);
}
__global__ void k_mol_acc(const unsigned short* __restrict__ xs, const float* __restrict__ a,
                          float* __restrict__ num, int n, int chunk){
  int t = threadIdx.x; // 128
  int start = blockIdx.x*chunk;
  int end = min(start + chunk, n);
  float s = 0.f;
  for (int i = start; i < end; ++i) s += bf2f(xs[(size_t)i*H + t])*a[i];
  if (start < end) atomicAdd(&num[t], s);
}
__global__ void k_mol_final(const float* __restrict__ num, const float* __restrict__ gsum,
                            const float* __restrict__ molb, const float* __restrict__ hidvec,
                            const float* __restrict__ Wih, const float* __restrict__ Whh,
                            const float* __restrict__ bih, const float* __restrict__ bhh,
                            float* __restrict__ out){
  __shared__ float hv[128], hd[128];
  int t = threadIdx.x;
  hv[t] = eluf(num[t]/gsum[0] + molb[t]);
  hd[t] = hidvec[t];
  __syncthreads();
  float gr = bih[t], gz = bih[t+128], gn = bih[t+256];
  float hr = bhh[t], hz = bhh[t+128], hn = bhh[t+256];
  for (int k = 0; k < 128; ++k){
    float h = hv[k], d = hd[k];
    gr += h*Wih[t*128+k];       gz += h*Wih[(t+128)*128+k]; gn += h*Wih[(t+256)*128+k];
    hr += d*Whh[t*128+k];       hz += d*Whh[(t+128)*128+k]; hn += d*Whh[(t+256)*128+k];
  }
  float r = sigm(gr+hr), z = sigm(gz+hz);
  float nn = tanhf(gn + r*hn);
  float o = (1.f-z)*nn + z*hd[t];
  out[t] = fmaxf(o, 0.f);
}

extern "C" void kernel_launch(void* const* d_in, const int* in_sizes, int n_in,
                              void* d_out, int out_size, void* d_ws, size_t ws_size,
                              hipStream_t stream){
  const float* node_attr = (const float*)d_in[0];
  const int*   eidx      = (const int*)d_in[1];
  const float* eattr     = (const float*)d_in[2];
  const float* W_lin1    = (const float*)d_in[3];
  const float* b_lin1    = (const float*)d_in[4];
  const float* gate_W1   = (const float*)d_in[5];
  const float* gate_W2   = (const float*)d_in[6];
  const float* gate_att_l= (const float*)d_in[7];
  const float* gate_att_r= (const float*)d_in[8];
  const float* gate_b    = (const float*)d_in[9];
  const float* g1_Wih    = (const float*)d_in[10];
  const float* g1_Whh    = (const float*)d_in[11];
  const float* g1_bih    = (const float*)d_in[12];
  const float* g1_bhh    = (const float*)d_in[13];
  const float* atom_W    = (const float*)d_in[14];
  const float* atom_as   = (const float*)d_in[15];
  const float* atom_ad   = (const float*)d_in[16];
  const float* atom_b    = (const float*)d_in[17];
  const float* g2_Wih    = (const float*)d_in[18];
  const float* g2_Whh    = (const float*)d_in[19];
  const float* g2_bih    = (const float*)d_in[20];
  const float* g2_bhh    = (const float*)d_in[21];
  const float* mol_W     = (const float*)d_in[22];
  const float* mol_as    = (const float*)d_in[23];
  const float* mol_ad    = (const float*)d_in[24];
  const float* mol_b     = (const float*)d_in[25];
  const float* gm_Wih    = (const float*)d_in[26];
  const float* gm_Whh    = (const float*)d_in[27];
  const float* gm_bih    = (const float*)d_in[28];
  const float* gm_bhh    = (const float*)d_in[29];

  const int n  = in_sizes[0];
  const int ne = in_sizes[1] / 2;
  const int* src = eidx;
  const int* dst = eidx + ne;

  // ---- workspace layout ----
  const size_t NH = (size_t)n * H;
  unsigned short* us = (unsigned short*)d_ws;
  unsigned short* x_bf = us;            // [N,H]
  unsigned short* t0   = us + NH;       // [N,H]
  unsigned short* t1   = us + 2*NH;     // [N,H]
  unsigned short* hb   = us + 3*NH;     // [N,H]
  unsigned short* gi   = us + 4*NH;     // [N,384]
  unsigned short* gh   = us + 7*NH;     // [N,384]
  float* fb = (float*)(us + 10*NH);
  float* rdot = fb;                     // [N]
  float* ssrc = rdot + n;               // [N]
  float* sdst = ssrc + n;               // [N]
  float* ealpha = sdst + n;             // [E]
  int* deg    = (int*)(ealpha + ne);    // [N]
  int* cursor = deg + n;                // [N]
  int* rowptr = cursor + n;             // [N+1]
  int* bsum   = rowptr + n + 1;         // [256]
  int* eid    = bsum + 256;             // [E]
  float* outraw = (float*)(eid + ne);   // [128]
  float* hidvec = outraw + 128;         // [128]
  float* cdstp  = hidvec + 128;         // [1]
  unsigned* gmax = (unsigned*)(cdstp + 1);
  float* gsum   = (float*)gmax + 1;
  float* numv   = gsum + 1;             // [128]
  float* w1col  = numv + 128;           // [128]
  unsigned short* wp = (unsigned short*)(w1col + 128);
  unsigned short* gW1bf  = wp;                 // 128*128
  unsigned short* gW2bf  = gW1bf  + 128*H;
  unsigned short* atomWbf= gW2bf  + 128*H;
  unsigned short* molWbf = atomWbf+ 128*H;
  unsigned short* g1ihbf = molWbf + 128*H;     // 384*128
  unsigned short* g1hhbf = g1ihbf + 384*H;
  unsigned short* g2ihbf = g1hhbf + 384*H;
  unsigned short* g2hhbf = g2ihbf + 384*H;

  const int nh_blocks  = (n*H + 255)/256;
  const int nb64       = (n + 63)/64;
  const int nwave4     = (n + 3)/4;
  const int e16_blocks = (ne + 15)/16;
  const int ethr       = (ne + 255)/256;
  const int nthr       = (n + 255)/256;
  const int nb         = (n + 255)/256;
  const int chunk      = (n + 255)/256;
  const int wcast128   = (128*H + 255)/256;
  const int wcast384   = (384*H + 255)/256;

  // ---- weight casts + CSR build + node init ----
  k_castw<<<wcast128,256,0,stream>>>(gate_W1, gW1bf, 128, 129);
  k_castw<<<wcast128,256,0,stream>>>(gate_W2, gW2bf, 128, 128);
  k_castw<<<wcast128,256,0,stream>>>(atom_W, atomWbf, 128, 128);
  k_castw<<<wcast128,256,0,stream>>>(mol_W, molWbf, 128, 128);
  k_castw<<<wcast384,256,0,stream>>>(g1_Wih, g1ihbf, 384, 128);
  k_castw<<<wcast384,256,0,stream>>>(g1_Whh, g1hhbf, 384, 128);
  k_castw<<<wcast384,256,0,stream>>>(g2_Wih, g2ihbf, 384, 128);
  k_castw<<<wcast384,256,0,stream>>>(g2_Whh, g2hhbf, 384, 128);
  k_pack_gate<<<1,128,0,stream>>>(gate_W1, w1col);
  k_node_init<<<nh_blocks,256,0,stream>>>(node_attr, W_lin1, b_lin1, x_bf, n);
  hipMemsetAsync(deg, 0, (size_t)n*4, stream);
  k_hist<<<ethr,256,0,stream>>>(dst, deg, ne);
  k_scan1<<<nb,256,0,stream>>>(deg, bsum, n);
  k_scan2<<<1,256,0,stream>>>(bsum, nb);
  k_scan3<<<nb,256,0,stream>>>(deg, bsum, rowptr, cursor, n);
  k_fill<<<ethr,256,0,stream>>>(dst, cursor, eid, ne);

  // ---- GATEConv ----
  k_gemm_mfma<<<dim3(nb64,1),256,0,stream>>>(x_bf, gW1bf, t0, n, H);   // xW1
  k_gemm_mfma<<<dim3(nb64,1),256,0,stream>>>(x_bf, gW2bf, t1, n, H);   // xW2
  k_rowdot2<<<nwave4,256,0,stream>>>(x_bf, gate_att_r, nullptr, rdot, nullptr, n);
  k_edge_logit_gate<<<e16_blocks,256,0,stream>>>(t0, w1col, gate_att_l, rdot, eattr,
                                                 src, dst, ealpha, ne);
  k_node_agg<<<nwave4,256,0,stream>>>(rowptr, eid, src, ealpha, t1, gate_b, hb, n);
  k_gemm_mfma<<<dim3(nb64,3),256,0,stream>>>(hb,   g1ihbf, gi, n, 384);
  k_gemm_mfma<<<dim3(nb64,3),256,0,stream>>>(x_bf, g1hhbf, gh, n, 384);
  k_gru_combine<<<nh_blocks,256,0,stream>>>(gi, gh, g1_bih, g1_bhh, x_bf, n);

  // ---- GATConv ----
  k_gemm_mfma<<<dim3(nb64,1),256,0,stream>>>(x_bf, atomWbf, t0, n, H); // xt
  k_rowdot2<<<nwave4,256,0,stream>>>(t0, atom_as, atom_ad, ssrc, sdst, n);
  k_node_agg_gat<<<nwave4,256,0,stream>>>(rowptr, eid, src, ssrc, sdst, t0, atom_b, hb, n);
  k_gemm_mfma<<<dim3(nb64,3),256,0,stream>>>(hb,   g2ihbf, gi, n, 384);
  k_gemm_mfma<<<dim3(nb64,3),256,0,stream>>>(x_bf, g2hhbf, gh, n, 384);
  k_gru_combine<<<nh_blocks,256,0,stream>>>(gi, gh, g2_bih, g2_bhh, x_bf, n);

  // ---- molecule readout ----
  hipMemsetAsync(outraw, 0, 128*4, stream);
  hipMemsetAsync(gmax, 0, 4, stream);
  hipMemsetAsync(gsum, 0, 4, stream);
  hipMemsetAsync(numv, 0, 128*4, stream);
  k_colsum<<<256,128,0,stream>>>(x_bf, outraw, n, chunk);
  k_mol_prep<<<1,128,0,stream>>>(outraw, mol_W, mol_ad, hidvec, cdstp);
  k_gemm_mfma<<<dim3(nb64,1),256,0,stream>>>(x_bf, molWbf, t1, n, H);  // xs
  k_rowdot2<<<nwave4,256,0,stream>>>(t1, mol_as, nullptr, rdot, nullptr, n);
  k_mol_logit<<<nthr,256,0,stream>>>(rdot, cdstp, gmax, n);
  k_mol_exp<<<nthr,256,0,stream>>>(rdot, gmax, gsum, n);
  k_mol_acc<<<256,128,0,stream>>>(t1, rdot, numv, n, chunk);
  k_mol_final<<<1,128,0,stream>>>(numv, gsum, mol_b, hidvec,
                                  gm_Wih, gm_Whh, gm_bih, gm_bhh, (float*)d_out);
}

// Round 8
// 741.403 us; speedup vs baseline: 1.0994x; 1.0316x over previous
//
#include <hip/hip_runtime.h>
#include <math.h>

#define H 128
#define NEGS 0.01f

typedef __attribute__((ext_vector_type(8))) short short8;
typedef __attribute__((ext_vector_type(4))) float f32x4;

__device__ __forceinline__ float lrelu(float x){ return x >= 0.f ? x : NEGS*x; }
__device__ __forceinline__ float eluf(float x){ return x > 0.f ? x : expf(x)-1.f; }
__device__ __forceinline__ float sigm(float x){ return 1.f/(1.f+expf(-x)); }
__device__ __forceinline__ float wred(float v){
  #pragma unroll
  for (int off = 32; off > 0; off >>= 1) v += __shfl_xor(v, off, 64);
  return v;
}
__device__ __forceinline__ float wredmax(float v){
  #pragma unroll
  for (int off = 32; off > 0; off >>= 1) v = fmaxf(v, __shfl_xor(v, off, 64));
  return v;
}
__device__ __forceinline__ unsigned fenc(float f){
  unsigned u = __float_as_uint(f);
  return (u & 0x80000000u) ? ~u : (u | 0x80000000u);
}
__device__ __forceinline__ float fdec(unsigned v){
  return __uint_as_float((v & 0x80000000u) ? (v ^ 0x80000000u) : ~v);
}
__device__ __forceinline__ unsigned short f2bf(float f){
  unsigned u = __float_as_uint(f);
  u += 0x7fffu + ((u >> 16) & 1u);
  return (unsigned short)(u >> 16);
}
__device__ __forceinline__ float bf2f(unsigned short h){
  return __uint_as_float(((unsigned)h) << 16);
}
__device__ __forceinline__ float rdlane(float v, int l){
  return __int_as_float(__builtin_amdgcn_readlane(__float_as_int(v), l));
}
__device__ __forceinline__ int rdlanei(int v, int l){
  return __builtin_amdgcn_readlane(v, l);
}

// one kernel casts all 8 weight matrices into the contiguous bf16 region
__global__ void k_castall(const float* __restrict__ gW1, const float* __restrict__ gW2,
                          const float* __restrict__ atomW, const float* __restrict__ molW,
                          const float* __restrict__ g1ih, const float* __restrict__ g1hh,
                          const float* __restrict__ g2ih, const float* __restrict__ g2hh,
                          unsigned short* __restrict__ dst){
  int idx = blockIdx.x*256 + threadIdx.x;   // total 262144
  const float* src; int ld = 128; int off;
  if      (idx <  16384){ src = gW1;  ld = 129; off = idx; }
  else if (idx <  32768){ src = gW2;  off = idx -  16384; }
  else if (idx <  49152){ src = atomW;off = idx -  32768; }
  else if (idx <  65536){ src = molW; off = idx -  49152; }
  else if (idx < 114688){ src = g1ih; off = idx -  65536; }
  else if (idx < 163840){ src = g1hh; off = idx - 114688; }
  else if (idx < 212992){ src = g2ih; off = idx - 163840; }
  else                  { src = g2hh; off = idx - 212992; }
  int r = off >> 7, c = off & 127;
  dst[idx] = f2bf(src[r*ld + c]);
}

// fused node init + rdot: x[i,:] = lrelu(na[i]*wl + bl) (bf16), rdot[i] = x[i,:].att_r
__global__ void k_node_init_rd(const float* __restrict__ na, const float* __restrict__ wl,
                               const float* __restrict__ bl, const float* __restrict__ attr,
                               unsigned short* __restrict__ x, float* __restrict__ rdot, int n){
  int i = blockIdx.x*4 + (threadIdx.x >> 6);
  int lane = threadIdx.x & 63;
  if (i >= n) return;
  float nav = na[i];
  float v0 = lrelu(nav*wl[2*lane]   + bl[2*lane]);
  float v1 = lrelu(nav*wl[2*lane+1] + bl[2*lane+1]);
  ushort2 o; o.x = f2bf(v0); o.y = f2bf(v1);
  *(ushort2*)&x[(size_t)i*H + 2*lane] = o;
  float d = bf2f(o.x)*attr[2*lane] + bf2f(o.y)*attr[2*lane+1];
  d = wred(d);
  if (lane == 0) rdot[i] = d;
}

// MFMA GEMM: Y[i*ldy + mbase + m] = sum_k X[i,k]*W[mbase+m,k]; bf16 in/out, f32 accum.
// Optional epilogue row-dots: o1[i] = Y[i,:].v1, o2[i] = Y[i,:].v2 (f32 acc precision).
__global__ __launch_bounds__(256)
void k_gemm_mfma(const unsigned short* __restrict__ X, const unsigned short* __restrict__ Wbf,
                 unsigned short* __restrict__ Y, int n, int ldy,
                 const float* __restrict__ v1, const float* __restrict__ v2,
                 float* __restrict__ o1, float* __restrict__ o2){
  int w = threadIdx.x >> 6;
  int l = threadIdx.x & 63;
  int i0 = blockIdx.x*64 + w*16;
  int mbase = blockIdx.y*128;
  int row = l & 15;
  int kg  = l >> 4;
  f32x4 acc[8];
  #pragma unroll
  for (int c = 0; c < 8; ++c) acc[c] = (f32x4){0.f,0.f,0.f,0.f};
  int ai = i0 + row;
  bool av = (ai < n);
  #pragma unroll
  for (int ks = 0; ks < 4; ++ks){
    int koff = ks*32 + kg*8;
    short8 a = av ? *(const short8*)&X[(size_t)ai*H + koff]
                  : (short8){0,0,0,0,0,0,0,0};
    #pragma unroll
    for (int c = 0; c < 8; ++c){
      short8 b = *(const short8*)&Wbf[(size_t)(mbase + c*16 + row)*H + koff];
      acc[c] = __builtin_amdgcn_mfma_f32_16x16x32_bf16(a, b, acc[c], 0, 0, 0);
    }
  }
  #pragma unroll
  for (int c = 0; c < 8; ++c){
    #pragma unroll
    for (int r = 0; r < 4; ++r){
      int i = i0 + kg*4 + r;
      if (i < n) Y[(size_t)i*ldy + mbase + c*16 + row] = f2bf(acc[c][r]);
    }
  }
  if (v1){
    #pragma unroll
    for (int r = 0; r < 4; ++r){
      float p1 = 0.f, p2 = 0.f;
      #pragma unroll
      for (int c = 0; c < 8; ++c){
        float av1 = v1[c*16 + row];
        p1 += acc[c][r]*av1;
        if (v2) p2 += acc[c][r]*v2[c*16 + row];
      }
      #pragma unroll
      for (int off = 1; off < 16; off <<= 1){
        p1 += __shfl_xor(p1, off, 64);
        if (v2) p2 += __shfl_xor(p2, off, 64);
      }
      int i = i0 + kg*4 + r;
      if (row == 0 && i < n){ o1[i] = p1; if (v2) o2[i] = p2; }
    }
  }
}

// GRUCell combine (bf16 gi/gh/x, ushort2-vectorized): x = relu((1-z)*n + z*x)
__global__ void k_gru_combine(const unsigned short* __restrict__ gi, const unsigned short* __restrict__ gh,
                              const float* __restrict__ bih, const float* __restrict__ bhh,
                              unsigned short* __restrict__ x, int n){
  int idx = blockIdx.x*blockDim.x + threadIdx.x;  // over n*64
  if (idx >= n*64) return;
  int i = idx >> 6, t = (idx & 63)*2;
  const unsigned short* gir = gi + (size_t)i*384;
  const unsigned short* ghr = gh + (size_t)i*384;
  ushort2 uir = *(const ushort2*)&gir[t];
  ushort2 uiz = *(const ushort2*)&gir[t+128];
  ushort2 uin = *(const ushort2*)&gir[t+256];
  ushort2 uhr = *(const ushort2*)&ghr[t];
  ushort2 uhz = *(const ushort2*)&ghr[t+128];
  ushort2 uhn = *(const ushort2*)&ghr[t+256];
  ushort2 ux  = *(const ushort2*)&x[(size_t)i*H + t];
  float2 b_ir = *(const float2*)&bih[t], b_iz = *(const float2*)&bih[t+128], b_in = *(const float2*)&bih[t+256];
  float2 b_hr = *(const float2*)&bhh[t], b_hz = *(const float2*)&bhh[t+128], b_hn = *(const float2*)&bhh[t+256];
  ushort2 o;
  {
    float r = sigm(bf2f(uir.x)+b_ir.x + bf2f(uhr.x)+b_hr.x);
    float z = sigm(bf2f(uiz.x)+b_iz.x + bf2f(uhz.x)+b_hz.x);
    float nn = tanhf(bf2f(uin.x)+b_in.x + r*(bf2f(uhn.x)+b_hn.x));
    o.x = f2bf(fmaxf((1.f-z)*nn + z*bf2f(ux.x), 0.f));
  }
  {
    float r = sigm(bf2f(uir.y)+b_ir.y + bf2f(uhr.y)+b_hr.y);
    float z = sigm(bf2f(uiz.y)+b_iz.y + bf2f(uhz.y)+b_hz.y);
    float nn = tanhf(bf2f(uin.y)+b_in.y + r*(bf2f(uhn.y)+b_hn.y));
    o.y = f2bf(fmaxf((1.f-z)*nn + z*bf2f(ux.y), 0.f));
  }
  *(ushort2*)&x[(size_t)i*H + t] = o;
}

// ---------------- CSR build ----------------
__global__ void k_hist(const int* __restrict__ dst, int* __restrict__ deg, int ne){
  int e = blockIdx.x*blockDim.x + threadIdx.x;
  if (e < ne) atomicAdd(&deg[dst[e]], 1);
}
__global__ void k_scan1(const int* __restrict__ deg, int* __restrict__ bsum, int n){
  __shared__ int sd[256];
  int i = blockIdx.x*256 + threadIdx.x;
  sd[threadIdx.x] = (i < n) ? deg[i] : 0;
  __syncthreads();
  for (int s = 128; s > 0; s >>= 1){
    if (threadIdx.x < s) sd[threadIdx.x] += sd[threadIdx.x+s];
    __syncthreads();
  }
  if (threadIdx.x == 0) bsum[blockIdx.x] = sd[0];
}
__global__ void k_scan2(int* __restrict__ bsum, int nb){
  __shared__ int sd[256];
  int t = threadIdx.x;
  int v = (t < nb) ? bsum[t] : 0;
  sd[t] = v;
  __syncthreads();
  for (int off = 1; off < 256; off <<= 1){
    int u = (t >= off) ? sd[t-off] : 0;
    __syncthreads();
    sd[t] += u;
    __syncthreads();
  }
  if (t < nb) bsum[t] = sd[t] - v;
}
__global__ void k_scan3(const int* __restrict__ deg, const int* __restrict__ boff,
                        int* __restrict__ rowptr, int* __restrict__ cursor, int n){
  __shared__ int sd[256];
  int t = threadIdx.x;
  int i = blockIdx.x*256 + t;
  int v = (i < n) ? deg[i] : 0;
  sd[t] = v;
  __syncthreads();
  for (int off = 1; off < 256; off <<= 1){
    int u = (t >= off) ? sd[t-off] : 0;
    __syncthreads();
    sd[t] += u;
    __syncthreads();
  }
  int excl = sd[t] - v + boff[blockIdx.x];
  if (i < n){
    rowptr[i] = excl; cursor[i] = excl;
    if (i == n-1) rowptr[n] = excl + v;
  }
}
__global__ void k_fill(const int* __restrict__ dst, int* __restrict__ cursor,
                       int* __restrict__ eid, int ne){
  int e = blockIdx.x*blockDim.x + threadIdx.x;
  if (e >= ne) return;
  int pos = atomicAdd(&cursor[dst[e]], 1);
  eid[pos] = e;
}

// contiguous copy of gate_W1[:,128]
__global__ void k_pack_gate(const float* __restrict__ gateW1, float* __restrict__ w1col){
  int t = threadIdx.x;
  if (t < H) w1col[t] = gateW1[t*129 + 128];
}

// GATEConv edge logits, 8 lanes/edge (8 edges/wave, 32/block), bf16 xW1
__global__ __launch_bounds__(256)
void k_edge_logit_gate(const unsigned short* __restrict__ xW1, const float* __restrict__ w1col,
                       const float* __restrict__ attl, const float* __restrict__ rdot,
                       const float* __restrict__ ea, const int* __restrict__ src,
                       const int* __restrict__ dst, float* __restrict__ logit, int ne){
  int tid = threadIdx.x;
  int e = blockIdx.x*32 + (tid >> 3);
  int g = tid & 7;
  if (e >= ne) return;
  int s = src[e];
  float eav = ea[e];
  const unsigned short* xr = &xW1[(size_t)s*H + g*16];
  short8 r0 = *(const short8*)xr;
  short8 r1 = *(const short8*)(xr + 8);
  float acc = 0.f;
  #pragma unroll
  for (int k = 0; k < 8; ++k)
    acc += lrelu(bf2f((unsigned short)r0[k]) + eav*w1col[g*16 + k]) * attl[g*16 + k];
  #pragma unroll
  for (int k = 0; k < 8; ++k)
    acc += lrelu(bf2f((unsigned short)r1[k]) + eav*w1col[g*16 + 8 + k]) * attl[g*16 + 8 + k];
  #pragma unroll
  for (int off = 1; off < 8; off <<= 1) acc += __shfl_xor(acc, off, 64);
  if (g == 0) logit[e] = lrelu(acc + rdot[dst[e]]);
}

// ---------------- per-node softmax + aggregation ----------------
// chunk-64 scheme, 8-deep unrolled gather loop
__global__ void k_node_agg(const int* __restrict__ rowptr, const int* __restrict__ eid,
                           const int* __restrict__ src, const float* __restrict__ logit,
                           const unsigned short* __restrict__ val, const float* __restrict__ bias,
                           unsigned short* __restrict__ hbuf, int n){
  int i = blockIdx.x*4 + (threadIdx.x >> 6);
  int lane = threadIdx.x & 63;
  if (i >= n) return;
  int b = rowptr[i], e1 = rowptr[i+1];
  float m = -1e30f;
  for (int j = b+lane; j < e1; j += 64) m = fmaxf(m, logit[eid[j]]);
  m = wredmax(m);
  float s = 0.f, ax = 0.f, ay = 0.f;
  for (int c0 = b; c0 < e1; c0 += 64){
    int cnt = min(64, e1 - c0);
    float wv = 0.f; int snv = 0;
    if (lane < cnt){
      int e = eid[c0 + lane];
      snv = src[e];
      wv = expf(logit[e] - m);
    }
    s += wred(wv);
    int j = 0;
    for (; j+8 <= cnt; j += 8){
      #pragma unroll
      for (int u = 0; u < 8; ++u){
        float wq = rdlane(wv, j+u);
        int sq = rdlanei(snv, j+u);
        ushort2 v = *(const ushort2*)&val[(size_t)sq*H + 2*lane];
        ax += bf2f(v.x)*wq; ay += bf2f(v.y)*wq;
      }
    }
    for (; j < cnt; ++j){
      float wq = rdlane(wv, j);
      int sq = rdlanei(snv, j);
      ushort2 v = *(const ushort2*)&val[(size_t)sq*H + 2*lane];
      ax += bf2f(v.x)*wq; ay += bf2f(v.y)*wq;
    }
  }
  float inv = (s > 0.f) ? 1.f/s : 0.f;
  ushort2 o;
  o.x = f2bf(eluf(bias[2*lane]   + ax*inv));
  o.y = f2bf(eluf(bias[2*lane+1] + ay*inv));
  *(ushort2*)&hbuf[(size_t)i*H + 2*lane] = o;
}

// GAT variant: logit = lrelu(ssrc[src]+sdst[i]) inline
__global__ void k_node_agg_gat(const int* __restrict__ rowptr, const int* __restrict__ eid,
                               const int* __restrict__ src, const float* __restrict__ ssrc,
                               const float* __restrict__ sdst, const unsigned short* __restrict__ val,
                               const float* __restrict__ bias, unsigned short* __restrict__ hbuf, int n){
  int i = blockIdx.x*4 + (threadIdx.x >> 6);
  int lane = threadIdx.x & 63;
  if (i >= n) return;
  int b = rowptr[i], e1 = rowptr[i+1];
  float sdi = sdst[i];
  float m = -1e30f;
  for (int j = b+lane; j < e1; j += 64) m = fmaxf(m, lrelu(ssrc[src[eid[j]]] + sdi));
  m = wredmax(m);
  float s = 0.f, ax = 0.f, ay = 0.f;
  for (int c0 = b; c0 < e1; c0 += 64){
    int cnt = min(64, e1 - c0);
    float wv = 0.f; int snv = 0;
    if (lane < cnt){
      snv = src[eid[c0 + lane]];
      wv = expf(lrelu(ssrc[snv] + sdi) - m);
    }
    s += wred(wv);
    int j = 0;
    for (; j+8 <= cnt; j += 8){
      #pragma unroll
      for (int u = 0; u < 8; ++u){
        float wq = rdlane(wv, j+u);
        int sq = rdlanei(snv, j+u);
        ushort2 v = *(const ushort2*)&val[(size_t)sq*H + 2*lane];
        ax += bf2f(v.x)*wq; ay += bf2f(v.y)*wq;
      }
    }
    for (; j < cnt; ++j){
      float wq = rdlane(wv, j);
      int sq = rdlanei(snv, j);
      ushort2 v = *(const ushort2*)&val[(size_t)sq*H + 2*lane];
      ax += bf2f(v.x)*wq; ay += bf2f(v.y)*wq;
    }
  }
  float inv = (s > 0.f) ? 1.f/s : 0.f;
  ushort2 o;
  o.x = f2bf(eluf(bias[2*lane]   + ax*inv));
  o.y = f2bf(eluf(bias[2*lane+1] + ay*inv));
  *(ushort2*)&hbuf[(size_t)i*H + 2*lane] = o;
}

// ---------------- molecule readout ----------------
__global__ void k_colsum(const unsigned short* __restrict__ x, float* __restrict__ outraw,
                         int n, int chunk){
  int t = threadIdx.x; // 64
  int start = blockIdx.x*chunk;
  int end = min(start + chunk, n);
  float s0 = 0.f, s1 = 0.f;
  for (int i = start; i < end; ++i){
    ushort2 v = *(const ushort2*)&x[(size_t)i*H + 2*t];
    s0 += bf2f(v.x); s1 += bf2f(v.y);
  }
  if (start < end){ atomicAdd(&outraw[2*t], s0); atomicAdd(&outraw[2*t+1], s1); }
}
__global__ void k_mol_prep(const float* __restrict__ outraw, const float* __restrict__ molW,
                           const float* __restrict__ attdst, float* __restrict__ hidvec,
                           float* __restrict__ cdst){
  __shared__ float hs[128];
  __shared__ float red[128];
  int t = threadIdx.x;
  float hv = fmaxf(outraw[t], 0.f);
  hs[t] = hv; hidvec[t] = hv;
  __syncthreads();
  float o = 0.f;
  for (int k = 0; k < 128; ++k) o += hs[k]*molW[t*128+k];
  red[t] = o * attdst[t];
  __syncthreads();
  for (int s = 64; s > 0; s >>= 1){
    if (t < s) red[t] += red[t+s];
    __syncthreads();
  }
  if (t == 0) cdst[0] = red[0];
}
__global__ void k_mol_logit(float* __restrict__ a, const float* __restrict__ cdst,
                            unsigned* __restrict__ gmax, int n){
  int i = blockIdx.x*blockDim.x + threadIdx.x;
  if (i >= n) return;
  float l = lrelu(a[i] + cdst[0]);
  a[i] = l;
  atomicMax(gmax, fenc(l));
}
__global__ void k_mol_exp(float* __restrict__ a, const unsigned* __restrict__ gmax,
                          float* __restrict__ gsum, int n){
  int i = blockIdx.x*blockDim.x + threadIdx.x;
  int lane = threadIdx.x & 63;
  float gm = fdec(gmax[0]);
  float ex = 0.f;
  if (i < n){ ex = expf(a[i] - gm); a[i] = ex; }
  float s = wred(ex);
  if (lane == 0) atomicAdd(gsum, s);
}
__global__ void k_mol_acc(const unsigned short* __restrict__ xs, const float* __restrict__ a,
                          float* __restrict__ num, int n, int chunk){
  int t = threadIdx.x; // 64
  int start = blockIdx.x*chunk;
  int end = min(start + chunk, n);
  float s0 = 0.f, s1 = 0.f;
  for (int i = start; i < end; ++i){
    float ai = a[i];
    ushort2 v = *(const ushort2*)&xs[(size_t)i*H + 2*t];
    s0 += bf2f(v.x)*ai; s1 += bf2f(v.y)*ai;
  }
  if (start < end){ atomicAdd(&num[2*t], s0); atomicAdd(&num[2*t+1], s1); }
}
__global__ void k_mol_final(const float* __restrict__ num, const float* __restrict__ gsum,
                            const float* __restrict__ molb, const float* __restrict__ hidvec,
                            const float* __restrict__ Wih, const float* __restrict__ Whh,
                            const float* __restrict__ bih, const float* __restrict__ bhh,
                            float* __restrict__ out){
  __shared__ float hv[128], hd[128];
  int t = threadIdx.x;
  hv[t] = eluf(num[t]/gsum[0] + molb[t]);
  hd[t] = hidvec[t];
  __syncthreads();
  float gr = bih[t], gz = bih[t+128], gn = bih[t+256];
  float hr = bhh[t], hz = bhh[t+128], hn = bhh[t+256];
  for (int k = 0; k < 128; ++k){
    float h = hv[k], d = hd[k];
    gr += h*Wih[t*128+k];       gz += h*Wih[(t+128)*128+k]; gn += h*Wih[(t+256)*128+k];
    hr += d*Whh[t*128+k];       hz += d*Whh[(t+128)*128+k]; hn += d*Whh[(t+256)*128+k];
  }
  float r = sigm(gr+hr), z = sigm(gz+hz);
  float nn = tanhf(gn + r*hn);
  float o = (1.f-z)*nn + z*hd[t];
  out[t] = fmaxf(o, 0.f);
}

extern "C" void kernel_launch(void* const* d_in, const int* in_sizes, int n_in,
                              void* d_out, int out_size, void* d_ws, size_t ws_size,
                              hipStream_t stream){
  const float* node_attr = (const float*)d_in[0];
  const int*   eidx      = (const int*)d_in[1];
  const float* eattr     = (const float*)d_in[2];
  const float* W_lin1    = (const float*)d_in[3];
  const float* b_lin1    = (const float*)d_in[4];
  const float* gate_W1   = (const float*)d_in[5];
  const float* gate_W2   = (const float*)d_in[6];
  const float* gate_att_l= (const float*)d_in[7];
  const float* gate_att_r= (const float*)d_in[8];
  const float* gate_b    = (const float*)d_in[9];
  const float* g1_Wih    = (const float*)d_in[10];
  const float* g1_Whh    = (const float*)d_in[11];
  const float* g1_bih    = (const float*)d_in[12];
  const float* g1_bhh    = (const float*)d_in[13];
  const float* atom_W    = (const float*)d_in[14];
  const float* atom_as   = (const float*)d_in[15];
  const float* atom_ad   = (const float*)d_in[16];
  const float* atom_b    = (const float*)d_in[17];
  const float* g2_Wih    = (const float*)d_in[18];
  const float* g2_Whh    = (const float*)d_in[19];
  const float* g2_bih    = (const float*)d_in[20];
  const float* g2_bhh    = (const float*)d_in[21];
  const float* mol_W     = (const float*)d_in[22];
  const float* mol_as    = (const float*)d_in[23];
  const float* mol_ad    = (const float*)d_in[24];
  const float* mol_b     = (const float*)d_in[25];
  const float* gm_Wih    = (const float*)d_in[26];
  const float* gm_Whh    = (const float*)d_in[27];
  const float* gm_bih    = (const float*)d_in[28];
  const float* gm_bhh    = (const float*)d_in[29];

  const int n  = in_sizes[0];
  const int ne = in_sizes[1] / 2;
  const int* src = eidx;
  const int* dst = eidx + ne;

  // ---- workspace layout ----
  const size_t NH = (size_t)n * H;
  unsigned short* us = (unsigned short*)d_ws;
  unsigned short* x_bf = us;            // [N,H]
  unsigned short* t0   = us + NH;       // [N,H]
  unsigned short* t1   = us + 2*NH;     // [N,H]
  unsigned short* hb   = us + 3*NH;     // [N,H]
  unsigned short* gi   = us + 4*NH;     // [N,384]
  unsigned short* gh   = us + 7*NH;     // [N,384]
  float* fb = (float*)(us + 10*NH);
  float* rdot = fb;                     // [N]
  float* ssrc = rdot + n;               // [N]
  float* sdst = ssrc + n;               // [N]
  float* ealpha = sdst + n;             // [E]
  int* deg    = (int*)(ealpha + ne);    // [N]
  int* cursor = deg + n;                // [N]
  int* rowptr = cursor + n;             // [N+1]
  int* bsum   = rowptr + n + 1;         // [256]
  int* eid    = bsum + 256;             // [E]
  float* outraw = (float*)(eid + ne);   // [128]
  float* hidvec = outraw + 128;         // [128]
  float* cdstp  = hidvec + 128;         // [1]
  unsigned* gmax = (unsigned*)(cdstp + 1);
  float* gsum   = (float*)gmax + 1;
  float* numv   = gsum + 1;             // [128]
  float* w1col  = numv + 128;           // [128]
  unsigned short* wp = (unsigned short*)(w1col + 128);
  unsigned short* gW1bf  = wp;                 // 128*128
  unsigned short* gW2bf  = gW1bf  + 128*H;
  unsigned short* atomWbf= gW2bf  + 128*H;
  unsigned short* molWbf = atomWbf+ 128*H;
  unsigned short* g1ihbf = molWbf + 128*H;     // 384*128
  unsigned short* g1hhbf = g1ihbf + 384*H;
  unsigned short* g2ihbf = g1hhbf + 384*H;
  unsigned short* g2hhbf = g2ihbf + 384*H;

  const int nb64       = (n + 63)/64;
  const int nwave4     = (n + 3)/4;
  const int e32_blocks = (ne + 31)/32;
  const int ethr       = (ne + 255)/256;
  const int nthr       = (n + 255)/256;
  const int nb         = (n + 255)/256;
  const int chunk      = (n + 255)/256;
  const int gru_blocks = (n*64 + 255)/256;

  // ---- weight casts + CSR build + node init (+fused GATE rowdot) ----
  k_castall<<<1024,256,0,stream>>>(gate_W1, gate_W2, atom_W, mol_W,
                                   g1_Wih, g1_Whh, g2_Wih, g2_Whh, wp);
  k_pack_gate<<<1,128,0,stream>>>(gate_W1, w1col);
  k_node_init_rd<<<nwave4,256,0,stream>>>(node_attr, W_lin1, b_lin1, gate_att_r, x_bf, rdot, n);
  hipMemsetAsync(deg, 0, (size_t)n*4, stream);
  k_hist<<<ethr,256,0,stream>>>(dst, deg, ne);
  k_scan1<<<nb,256,0,stream>>>(deg, bsum, n);
  k_scan2<<<1,256,0,stream>>>(bsum, nb);
  k_scan3<<<nb,256,0,stream>>>(deg, bsum, rowptr, cursor, n);
  k_fill<<<ethr,256,0,stream>>>(dst, cursor, eid, ne);

  // ---- GATEConv ----
  k_gemm_mfma<<<dim3(nb64,1),256,0,stream>>>(x_bf, gW1bf, t0, n, H,
                                             nullptr, nullptr, nullptr, nullptr);   // xW1
  k_gemm_mfma<<<dim3(nb64,1),256,0,stream>>>(x_bf, gW2bf, t1, n, H,
                                             nullptr, nullptr, nullptr, nullptr);   // xW2
  k_edge_logit_gate<<<e32_blocks,256,0,stream>>>(t0, w1col, gate_att_l, rdot, eattr,
                                                 src, dst, ealpha, ne);
  k_node_agg<<<nwave4,256,0,stream>>>(rowptr, eid, src, ealpha, t1, gate_b, hb, n);
  k_gemm_mfma<<<dim3(nb64,3),256,0,stream>>>(hb,   g1ihbf, gi, n, 384,
                                             nullptr, nullptr, nullptr, nullptr);
  k_gemm_mfma<<<dim3(nb64,3),256,0,stream>>>(x_bf, g1hhbf, gh, n, 384,
                                             nullptr, nullptr, nullptr, nullptr);
  k_gru_combine<<<gru_blocks,256,0,stream>>>(gi, gh, g1_bih, g1_bhh, x_bf, n);

  // ---- GATConv ----
  k_gemm_mfma<<<dim3(nb64,1),256,0,stream>>>(x_bf, atomWbf, t0, n, H,
                                             atom_as, atom_ad, ssrc, sdst);         // xt + dots
  k_node_agg_gat<<<nwave4,256,0,stream>>>(rowptr, eid, src, ssrc, sdst, t0, atom_b, hb, n);
  k_gemm_mfma<<<dim3(nb64,3),256,0,stream>>>(hb,   g2ihbf, gi, n, 384,
                                             nullptr, nullptr, nullptr, nullptr);
  k_gemm_mfma<<<dim3(nb64,3),256,0,stream>>>(x_bf, g2hhbf, gh, n, 384,
                                             nullptr, nullptr, nullptr, nullptr);
  k_gru_combine<<<gru_blocks,256,0,stream>>>(gi, gh, g2_bih, g2_bhh, x_bf, n);

  // ---- molecule readout ----
  hipMemsetAsync(outraw, 0, 128*4, stream);
  hipMemsetAsync(gmax, 0, 4, stream);
  hipMemsetAsync(gsum, 0, 4, stream);
  hipMemsetAsync(numv, 0, 128*4, stream);
  k_colsum<<<256,64,0,stream>>>(x_bf, outraw, n, chunk);
  k_mol_prep<<<1,128,0,stream>>>(outraw, mol_W, mol_ad, hidvec, cdstp);
  k_gemm_mfma<<<dim3(nb64,1),256,0,stream>>>(x_bf, molWbf, t1, n, H,
                                             mol_as, nullptr, rdot, nullptr);       // xs + dot
  k_mol_logit<<<nthr,256,0,stream>>>(rdot, cdstp, gmax, n);
  k_mol_exp<<<nthr,256,0,stream>>>(rdot, gmax, gsum, n);
  k_mol_acc<<<256,64,0,stream>>>(t1, rdot, numv, n, chunk);
  k_mol_final<<<1,128,0,stream>>>(numv, gsum, mol_b, hidvec,
                                  gm_Wih, gm_Whh, gm_bih, gm_bhh, (float*)d_out);
}